// Round 5
// baseline (4324.163 us; speedup 1.0000x reference)
//
#include <hip/hip_runtime.h>
#include <hip/hip_bf16.h>

#define DXc 256
#define DYc 32
#define Kc 4
#define Hc 128
#define LRf 0.1f
#define REGf 0.01f
#define TSTEPS 1000

typedef __attribute__((ext_vector_type(8))) short s8b;    // 8 x bf16 (4 VGPRs)
typedef __attribute__((ext_vector_type(4))) float f32x4;  // MFMA accumulator

#define MFMA16(a, b, c) __builtin_amdgcn_mfma_f32_16x16x32_bf16((a), (b), (c), 0, 0, 0)

// 6-product "f32-exact" MFMA: A=a0+a1+a2, B=b0+b1+b2 (exact 3-way bf16 splits).
#define MFMA6(A0, A1, A2, B0, B1, B2, acc)      \
    do {                                        \
        acc = MFMA16((A0), (B0), acc);          \
        acc = MFMA16((A0), (B1), acc);          \
        acc = MFMA16((A1), (B0), acc);          \
        acc = MFMA16((A0), (B2), acc);          \
        acc = MFMA16((A1), (B1), acc);          \
        acc = MFMA16((A2), (B0), acc);          \
    } while (0)

// ---- bf16 split helpers ----
__device__ __forceinline__ float hipart(float a) {
    return __uint_as_float(__float_as_uint(a) & 0xffff0000u);
}
__device__ __forceinline__ unsigned hi2(float a, float b) {
    return (__float_as_uint(a) >> 16) | (__float_as_uint(b) & 0xffff0000u);
}
__device__ __forceinline__ void wsplit(float x, unsigned short* __restrict__ h,
                                       unsigned short* __restrict__ l) {
    unsigned u = __float_as_uint(x);
    *h = (unsigned short)(u >> 16);
    float hf = __uint_as_float(u & 0xffff0000u);
    *l = (unsigned short)(__float_as_uint(x - hf) >> 16);
}
__device__ __forceinline__ void wsplit3(float x, unsigned short* __restrict__ p0,
                                        unsigned short* __restrict__ p1,
                                        unsigned short* __restrict__ p2) {
    unsigned u = __float_as_uint(x);
    *p0 = (unsigned short)(u >> 16);
    float r1 = x - __uint_as_float(u & 0xffff0000u);
    unsigned u1 = __float_as_uint(r1);
    *p1 = (unsigned short)(u1 >> 16);
    float r2 = r1 - __uint_as_float(u1 & 0xffff0000u);
    *p2 = (unsigned short)(__float_as_uint(r2) >> 16);
}
__device__ __forceinline__ void split3x8(const float* v, s8b& A0, s8b& A1, s8b& A2) {
    union { s8b s; unsigned u[4]; } P0, P1, P2;
    #pragma unroll
    for (int m = 0; m < 4; ++m) {
        float a = v[2 * m], b = v[2 * m + 1];
        unsigned ua = __float_as_uint(a), ub = __float_as_uint(b);
        P0.u[m] = (ua >> 16) | (ub & 0xffff0000u);
        float ra = a - __uint_as_float(ua & 0xffff0000u);
        float rb = b - __uint_as_float(ub & 0xffff0000u);
        unsigned ura = __float_as_uint(ra), urb = __float_as_uint(rb);
        P1.u[m] = (ura >> 16) | (urb & 0xffff0000u);
        float ra2 = ra - __uint_as_float(ura & 0xffff0000u);
        float rb2 = rb - __uint_as_float(urb & 0xffff0000u);
        P2.u[m] = (__float_as_uint(ra2) >> 16) | (__float_as_uint(rb2) & 0xffff0000u);
    }
    A0 = P0.s; A1 = P1.s; A2 = P2.s;
}
__device__ __forceinline__ void split3pack4(const float* v, uint2& Q0, uint2& Q1, uint2& Q2) {
    float r1[4], r2[4];
    #pragma unroll
    for (int i = 0; i < 4; ++i) {
        r1[i] = v[i] - hipart(v[i]);
        r2[i] = r1[i] - hipart(r1[i]);
    }
    Q0.x = hi2(v[0], v[1]);   Q0.y = hi2(v[2], v[3]);
    Q1.x = hi2(r1[0], r1[1]); Q1.y = hi2(r1[2], r1[3]);
    Q2.x = hi2(r2[0], r2[1]); Q2.y = hi2(r2[2], r2[3]);
}
__device__ __forceinline__ void split2pack4(const float* v, uint2& Q0, uint2& Q1) {
    Q0.x = hi2(v[0], v[1]); Q0.y = hi2(v[2], v[3]);
    float r0 = v[0] - hipart(v[0]), r1 = v[1] - hipart(v[1]);
    float r2 = v[2] - hipart(v[2]), r3 = v[3] - hipart(v[3]);
    Q1.x = hi2(r0, r1); Q1.y = hi2(r2, r3);
}

// ---------------------------------------------------------------------------
// Setup: derived weights into workspace (all bf16 split planes, k-contiguous).
//   WcatTb0/1/2 [256][256]: Wcat^T = [E | P]^T   (rowpre A-operand)
//   W1Tb0/1/2   [256][32] : W1^T = [Wy | M]^T    (P1 A-operand)
//   ew2Tb0/1/2  [128][128]: e_w2^T               (P3 A-operand)
//   ew2b h/l    [128][128]: e_w2 row-major       (P4 A-operand)
//   Wdy  h/l    [32][256] : [ M | Wy ]           (P5 A-operand)
//   d0 (4x128)  = temb@A2 + th@A3 + s_yb@A1 + s_xb@A0 + tr1b
// ---------------------------------------------------------------------------
__global__ __launch_bounds__(256) void setup_kernel(
    const float* __restrict__ e_w1, const float* __restrict__ s_xw,
    const float* __restrict__ s_yw, const float* __restrict__ s_temb,
    const float* __restrict__ s_t1w, const float* __restrict__ s_t1b,
    const float* __restrict__ s_t2w, const float* __restrict__ s_t2b,
    const float* __restrict__ tr1w, const float* __restrict__ tr1b,
    const float* __restrict__ s_xb, const float* __restrict__ s_yb,
    const float* __restrict__ e_w2, float* __restrict__ d0,
    unsigned short* __restrict__ WcatTb0, unsigned short* __restrict__ WcatTb1,
    unsigned short* __restrict__ WcatTb2,
    unsigned short* __restrict__ W1Tb0, unsigned short* __restrict__ W1Tb1,
    unsigned short* __restrict__ W1Tb2,
    unsigned short* __restrict__ ew2Tb0, unsigned short* __restrict__ ew2Tb1,
    unsigned short* __restrict__ ew2Tb2,
    unsigned short* __restrict__ ew2bh, unsigned short* __restrict__ ew2bl,
    unsigned short* __restrict__ Wdybh, unsigned short* __restrict__ Wdybl)
{
    const int b = blockIdx.x;
    const int t = threadIdx.x;
    if (b < 64) {
        #pragma unroll
        for (int i = 0; i < 2; ++i) {
            int idx = t + 256 * i;              // 0..511
            int k = 4 * b + (idx >> 7);
            int c = idx & 127;
            float acc = 0.f;
            for (int h = 0; h < 128; ++h)
                acc += s_xw[k * 128 + h] * tr1w[h * 128 + c];
            // WcatT[c][k]: E part (c) from e_w1, P part (128+c) computed
            wsplit3(acc, &WcatTb0[(128 + c) * 256 + k], &WcatTb1[(128 + c) * 256 + k],
                    &WcatTb2[(128 + c) * 256 + k]);
            float ev = e_w1[k * 128 + c];
            wsplit3(ev, &WcatTb0[c * 256 + k], &WcatTb1[c * 256 + k],
                    &WcatTb2[c * 256 + k]);
        }
    } else if (b == 64) {
        // M = s_yw @ A1   (W1 cols 128..255)
        #pragma unroll
        for (int i = 0; i < 16; ++i) {
            int idx = t + 256 * i;              // 0..4095
            int d = idx >> 7, c = idx & 127;
            float acc = 0.f;
            for (int h = 0; h < 128; ++h)
                acc += s_yw[d * 128 + h] * tr1w[(128 + h) * 128 + c];
            wsplit3(acc, &W1Tb0[(128 + c) * 32 + d], &W1Tb1[(128 + c) * 32 + d],
                    &W1Tb2[(128 + c) * 32 + d]);
            wsplit(acc, &Wdybh[d * 256 + c], &Wdybl[d * 256 + c]);
        }
    } else if (b == 65) {
        // Wy = e_w1[256:288]  (W1 cols 0..127)
        #pragma unroll
        for (int i = 0; i < 16; ++i) {
            int idx = t + 256 * i;
            int d = idx >> 7, c = idx & 127;
            float v = e_w1[(DXc + d) * 128 + c];
            wsplit3(v, &W1Tb0[c * 32 + d], &W1Tb1[c * 32 + d], &W1Tb2[c * 32 + d]);
            wsplit(v, &Wdybh[d * 256 + 128 + c], &Wdybl[d * 256 + 128 + c]);
        }
    } else if (b == 66) {
        // e_w2 splits (both orientations)
        #pragma unroll
        for (int i = 0; i < 64; ++i) {
            int idx = t + 256 * i;
            int h = idx >> 7, c = idx & 127;
            float v = e_w2[h * 128 + c];
            wsplit3(v, &ew2Tb0[c * 128 + h], &ew2Tb1[c * 128 + h],
                    &ew2Tb2[c * 128 + h]);
            wsplit(v, &ew2bh[h * 128 + c], &ew2bl[h * 128 + c]);
        }
    } else {
        // b == 67: th table then d0 table
        __shared__ float thS[4][128];
        #pragma unroll
        for (int i = 0; i < 2; ++i) {
            int idx = t + 256 * i;              // 0..511
            int tt = idx >> 7, c = idx & 127;
            float tau = (float)tt / (float)TSTEPS;
            if (tau < 1e-6f) tau = 1e-6f;
            float acc = s_t2b[c];
            for (int h = 0; h < 128; ++h) {
                float aa = tau * s_t1w[h] + s_t1b[h];
                float s = 1.f / (1.f + expf(-aa));
                acc += aa * s * s_t2w[h * 128 + c];
            }
            thS[tt][c] = acc;
        }
        __syncthreads();
        #pragma unroll
        for (int i = 0; i < 2; ++i) {
            int idx = t + 256 * i;
            int tt = idx >> 7, c = idx & 127;
            float acc = tr1b[c];
            for (int h = 0; h < 128; ++h) {
                acc += s_temb[tt * 128 + h] * tr1w[(256 + h) * 128 + c];
                acc += thS[tt][h]           * tr1w[(384 + h) * 128 + c];
                acc += s_yb[h]              * tr1w[(128 + h) * 128 + c];
                acc += s_xb[h]              * tr1w[h * 128 + c];
            }
            d0[tt * 128 + c] = acc;
        }
    }
}

// ---------------------------------------------------------------------------
// Row precompute (MFMA, transposed): [hxe|cb]^T = Wcat^T x x^T.
// 64 samples/block, 4 waves; wave owns 4 col-tiles; exact 3-plane/6-product.
// D lane: 4 consecutive out-cols for one sample -> float4 global stores.
// ---------------------------------------------------------------------------
__global__ __launch_bounds__(256) void rowpre_kernel(
    const float* __restrict__ x, const int* __restrict__ tin,
    const unsigned short* __restrict__ WcatTb0,
    const unsigned short* __restrict__ WcatTb1,
    const unsigned short* __restrict__ WcatTb2,
    const float* __restrict__ e_b1, const float* __restrict__ d0,
    float* __restrict__ hxeP, float* __restrict__ cbP)
{
    __shared__ int tS[64];
    const int t = threadIdx.x;
    const int r0 = blockIdx.x * 64;
    const int w = t >> 6;
    const int l = t & 63;
    const int g = l >> 4, q = l & 15;
    if (t < 64) { int tv = tin[r0 + t]; tS[t] = tv > 0 ? tv : 0; }
    __syncthreads();

    for (int st = 0; st < 4; ++st) {
        const int smp = r0 + st * 16 + q;
        s8b Xb0[8], Xb1[8], Xb2[8];
        #pragma unroll
        for (int kc = 0; kc < 8; ++kc) {
            const float* xp = &x[(size_t)smp * 256 + kc * 32 + g * 8];
            float4 xa = *(const float4*)xp;
            float4 xb = *(const float4*)(xp + 4);
            float xv[8] = {xa.x, xa.y, xa.z, xa.w, xb.x, xb.y, xb.z, xb.w};
            split3x8(xv, Xb0[kc], Xb1[kc], Xb2[kc]);
        }
        #pragma unroll
        for (int ci = 0; ci < 4; ++ci) {
            const int colt = w * 4 + ci;
            f32x4 acc = {0.f, 0.f, 0.f, 0.f};
            #pragma unroll
            for (int kc = 0; kc < 8; ++kc) {
                const int wo = (colt * 16 + q) * 256 + kc * 32 + g * 8;
                s8b A0 = *(const s8b*)&WcatTb0[wo];
                s8b A1 = *(const s8b*)&WcatTb1[wo];
                s8b A2 = *(const s8b*)&WcatTb2[wo];
                MFMA6(A0, A1, A2, Xb0[kc], Xb1[kc], Xb2[kc], acc);
            }
            const int cb = colt * 16 + g * 4;
            if (colt < 8) {
                float4 bv = *(const float4*)&e_b1[cb];
                float4 o = {acc[0] + bv.x, acc[1] + bv.y, acc[2] + bv.z, acc[3] + bv.w};
                *(float4*)&hxeP[(size_t)smp * 128 + cb] = o;
            } else {
                const int cc = cb - 128;
                float4 dd = *(const float4*)&d0[tS[st * 16 + q] * 128 + cc];
                float4 o = {acc[0] + dd.x, acc[1] + dd.y, acc[2] + dd.z, acc[3] + dd.w};
                *(float4*)&cbP[(size_t)smp * 128 + cc] = o;
            }
        }
    }
}

// ---------------------------------------------------------------------------
// Iterate kernel: 32 rows/block, 8 waves (512 thr), 20 GD steps.
// __launch_bounds__(512,4): VGPR<=128 -> 2 blocks/CU = 16 waves/CU.
// Wave owns fixed column-tiles, processes BOTH 16-sample halves -> each
// step-invariant weight A-frag load feeds 2x MFMA; W1 A-frags hoisted.
// tr2w held in registers (kills the p-invariant 8-way-conflict LDS reads).
// ---------------------------------------------------------------------------
__global__ __launch_bounds__(512, 4) void iterate_kernel(
    const float* __restrict__ hxeP, const float* __restrict__ cbP,
    const unsigned short* __restrict__ W1Tb0, const unsigned short* __restrict__ W1Tb1,
    const unsigned short* __restrict__ W1Tb2,
    const unsigned short* __restrict__ ew2Tb0, const unsigned short* __restrict__ ew2Tb1,
    const unsigned short* __restrict__ ew2Tb2,
    const unsigned short* __restrict__ ew2bh, const unsigned short* __restrict__ ew2bl,
    const unsigned short* __restrict__ Wdybh, const unsigned short* __restrict__ Wdybl,
    const float* __restrict__ e_w3, const float* __restrict__ tr2w,
    const float* __restrict__ tr2b, const float* __restrict__ e_b2,
    const int* __restrict__ tin, const int* __restrict__ stepsPtr,
    float* __restrict__ yout)
{
    __shared__ __align__(16) unsigned short H1a[32 * 136]; // h1 p0, then dz1 hi
    __shared__ __align__(16) unsigned short H1b[32 * 136]; // h1 p1, then dz1 lo
    __shared__ __align__(16) unsigned short H1c[32 * 136]; // h1 p2
    __shared__ __align__(16) unsigned short DAa[32 * 136], DAb[32 * 136]; // da hi/lo
    __shared__ __align__(16) float U[32 * 140];     // 'a' f32; then dz2 hi/lo bf16
    __shared__ __align__(16) float yS[32 * 36];     // y master f32 [sample][d]
    __shared__ float ew3S[512];
    __shared__ float eb2S[128];
    __shared__ float vSs[32];
    __shared__ int tcS[32];

    const int t = threadIdx.x;
    const int r0 = blockIdx.x * 32;
    const int w = t >> 6;        // wave 0..7
    const int l = t & 63;
    const int g = l >> 4;        // 0..3
    const int q = l & 15;        // 0..15
    const int row = t >> 4;      // P2 row 0..31
    const int p = t & 15;        // P2 h-slice

    if (t < 32) {
        int tv = tin[r0 + t];
        tcS[t] = tv > 0 ? tv : 0;
        vSs[t] = (tv >= 0) ? 1.f : 0.f;
    }
    if (t < 128) eb2S[t] = e_b2[t];
    ew3S[t] = e_w3[t];
    for (int i = t; i < 32 * 36; i += 512) yS[i] = 0.f;

    // tr2w rows for this thread's P2 slice: 8 x float4 = 32 VGPR
    float4 trw4[8];
    {
        const int h0 = p * 8;
        #pragma unroll
        for (int j = 0; j < 8; ++j)
            trw4[j] = *(const float4*)&tr2w[(h0 + j) * 4];
    }
    // W1^T A-fragments (loop-invariant): 2 col-tiles x 3 planes = 24 VGPR
    s8b W1A0[2], W1A1[2], W1A2[2];
    #pragma unroll
    for (int ci = 0; ci < 2; ++ci) {
        const int arow = (2 * w + ci) * 16 + q;
        W1A0[ci] = *(const s8b*)&W1Tb0[arow * 32 + g * 8];
        W1A1[ci] = *(const s8b*)&W1Tb1[arow * 32 + g * 8];
        W1A2[ci] = *(const s8b*)&W1Tb2[arow * 32 + g * 8];
    }
    const float tb0 = tr2b[0], tb1 = tr2b[1], tb2 = tr2b[2], tb3 = tr2b[3];
    const int nsteps = stepsPtr[0];

    __syncthreads();

    for (int step = 0; step < nsteps; ++step) {
        // ------- P1: z1^T = W1^T x y^T; waves 0-3 -> h1, waves 4-7 -> 'a' ----
        #pragma unroll
        for (int ct = 0; ct < 2; ++ct) {
            float4 ya = *(const float4*)&yS[(ct * 16 + q) * 36 + g * 8];
            float4 yb = *(const float4*)&yS[(ct * 16 + q) * 36 + g * 8 + 4];
            float yv[8] = {ya.x, ya.y, ya.z, ya.w, yb.x, yb.y, yb.z, yb.w};
            s8b Y0, Y1, Y2;
            split3x8(yv, Y0, Y1, Y2);
            #pragma unroll
            for (int ci = 0; ci < 2; ++ci) {
                const int colt = 2 * w + ci;
                f32x4 acc = {0.f, 0.f, 0.f, 0.f};
                MFMA6(W1A0[ci], W1A1[ci], W1A2[ci], Y0, Y1, Y2, acc);
                if (w < 4) {
                    const float4 vb = *(const float4*)
                        &hxeP[(size_t)(r0 + ct * 16 + q) * 128 + colt * 16 + g * 4];
                    float v[4];
                    v[0] = acc[0] + vb.x; v[1] = acc[1] + vb.y;
                    v[2] = acc[2] + vb.z; v[3] = acc[3] + vb.w;
                    #pragma unroll
                    for (int j = 0; j < 4; ++j) v[j] = v[j] > 0.f ? v[j] : 0.f;
                    uint2 Q0, Q1, Q2;
                    split3pack4(v, Q0, Q1, Q2);
                    const int off = (ct * 16 + q) * 136 + colt * 16 + g * 4;
                    *(uint2*)&H1a[off] = Q0;
                    *(uint2*)&H1b[off] = Q1;
                    *(uint2*)&H1c[off] = Q2;
                } else {
                    const int cc = (colt - 8) * 16 + g * 4;
                    const float4 vb = *(const float4*)
                        &cbP[(size_t)(r0 + ct * 16 + q) * 128 + cc];
                    float4 o = {acc[0] + vb.x, acc[1] + vb.y,
                                acc[2] + vb.z, acc[3] + vb.w};
                    *(float4*)&U[(ct * 16 + q) * 140 + cc] = o;
                }
            }
        }
        __syncthreads();

        // ---------------- P2: pointwise CE (f32); 32 rows x 16 lanes ---------
        {
            float aval[8], sval[8];
            float lg0 = 0.f, lg1 = 0.f, lg2 = 0.f, lg3 = 0.f;
            const int h0 = p * 8;
            const float* ap = &U[row * 140 + h0];
            float4 v0 = *(const float4*)ap;
            float4 v1 = *(const float4*)(ap + 4);
            aval[0] = v0.x; aval[1] = v0.y; aval[2] = v0.z; aval[3] = v0.w;
            aval[4] = v1.x; aval[5] = v1.y; aval[6] = v1.z; aval[7] = v1.w;
            #pragma unroll
            for (int j = 0; j < 8; ++j) {
                float a = aval[j];
                float s = 1.f / (1.f + __expf(-a));
                sval[j] = s;
                float u = a * s;
                lg0 += u * trw4[j].x; lg1 += u * trw4[j].y;
                lg2 += u * trw4[j].z; lg3 += u * trw4[j].w;
            }
            #pragma unroll
            for (int m = 1; m < 16; m <<= 1) {
                lg0 += __shfl_xor(lg0, m);
                lg1 += __shfl_xor(lg1, m);
                lg2 += __shfl_xor(lg2, m);
                lg3 += __shfl_xor(lg3, m);
            }
            lg0 += tb0; lg1 += tb1; lg2 += tb2; lg3 += tb3;
            float mx = fmaxf(fmaxf(lg0, lg1), fmaxf(lg2, lg3));
            float e0 = __expf(lg0 - mx), e1 = __expf(lg1 - mx);
            float e2 = __expf(lg2 - mx), e3 = __expf(lg3 - mx);
            float inv = 1.f / (e0 + e1 + e2 + e3);
            int tcr = tcS[row];
            float vd = vSs[row];
            float dl0 = (e0 * inv - (tcr == 0 ? 1.f : 0.f)) * vd;
            float dl1 = (e1 * inv - (tcr == 1 ? 1.f : 0.f)) * vd;
            float dl2 = (e2 * inv - (tcr == 2 ? 1.f : 0.f)) * vd;
            float dl3 = (e3 * inv - (tcr == 3 ? 1.f : 0.f)) * vd;
            #pragma unroll
            for (int j = 0; j < 8; ++j) {
                float a = aval[j], s = sval[j];
                float du = dl0 * trw4[j].x + dl1 * trw4[j].y
                         + dl2 * trw4[j].z + dl3 * trw4[j].w;
                aval[j] = du * s * (1.f + a * (1.f - s));   // da
            }
            const int off = row * 136 + h0;
            uint2 Qh0 = {hi2(aval[0], aval[1]), hi2(aval[2], aval[3])};
            uint2 Qh1 = {hi2(aval[4], aval[5]), hi2(aval[6], aval[7])};
            float rl[8];
            #pragma unroll
            for (int j = 0; j < 8; ++j) rl[j] = aval[j] - hipart(aval[j]);
            uint2 Ql0 = {hi2(rl[0], rl[1]), hi2(rl[2], rl[3])};
            uint2 Ql1 = {hi2(rl[4], rl[5]), hi2(rl[6], rl[7])};
            *(uint2*)&DAa[off] = Qh0;
            *(uint2*)&DAa[off + 4] = Qh1;
            *(uint2*)&DAb[off] = Ql0;
            *(uint2*)&DAb[off + 4] = Ql1;
        }
        __syncthreads();

        // ------- P3: z2^T = e_w2^T x h1^T (hi-prec); wave owns ctl=w --------
        {
            unsigned short* DZh = (unsigned short*)U;
            unsigned short* DZl = DZh + 32 * 136;
            f32x4 acc0 = {0.f, 0.f, 0.f, 0.f};
            f32x4 acc1 = {0.f, 0.f, 0.f, 0.f};
            #pragma unroll
            for (int kc = 0; kc < 4; ++kc) {
                const int b0 = q * 136 + kc * 32 + g * 8;
                const int b1 = (16 + q) * 136 + kc * 32 + g * 8;
                s8b B0a = *(const s8b*)&H1a[b0];
                s8b B0b = *(const s8b*)&H1b[b0];
                s8b B0c = *(const s8b*)&H1c[b0];
                s8b B1a = *(const s8b*)&H1a[b1];
                s8b B1b = *(const s8b*)&H1b[b1];
                s8b B1c = *(const s8b*)&H1c[b1];
                const int wo = (w * 16 + q) * 128 + kc * 32 + g * 8;
                s8b A0 = *(const s8b*)&ew2Tb0[wo];
                s8b A1 = *(const s8b*)&ew2Tb1[wo];
                s8b A2 = *(const s8b*)&ew2Tb2[wo];
                MFMA6(A0, A1, A2, B0a, B0b, B0c, acc0);
                MFMA6(A0, A1, A2, B1a, B1b, B1c, acc1);
            }
            const int cb = w * 16 + g * 4;
            const float4 eb = *(const float4*)&eb2S[cb];
            {   // ct = 0
                const int smp = q;
                const int tcr = tcS[smp];
                float dz[4];
                dz[0] = (acc0[0] + eb.x) > 0.f ? ew3S[(cb + 0) * 4 + tcr] : 0.f;
                dz[1] = (acc0[1] + eb.y) > 0.f ? ew3S[(cb + 1) * 4 + tcr] : 0.f;
                dz[2] = (acc0[2] + eb.z) > 0.f ? ew3S[(cb + 2) * 4 + tcr] : 0.f;
                dz[3] = (acc0[3] + eb.w) > 0.f ? ew3S[(cb + 3) * 4 + tcr] : 0.f;
                uint2 Q0, Q1;
                split2pack4(dz, Q0, Q1);
                *(uint2*)&DZh[smp * 136 + cb] = Q0;
                *(uint2*)&DZl[smp * 136 + cb] = Q1;
            }
            {   // ct = 1
                const int smp = 16 + q;
                const int tcr = tcS[smp];
                float dz[4];
                dz[0] = (acc1[0] + eb.x) > 0.f ? ew3S[(cb + 0) * 4 + tcr] : 0.f;
                dz[1] = (acc1[1] + eb.y) > 0.f ? ew3S[(cb + 1) * 4 + tcr] : 0.f;
                dz[2] = (acc1[2] + eb.z) > 0.f ? ew3S[(cb + 2) * 4 + tcr] : 0.f;
                dz[3] = (acc1[3] + eb.w) > 0.f ? ew3S[(cb + 3) * 4 + tcr] : 0.f;
                uint2 Q0, Q1;
                split2pack4(dz, Q0, Q1);
                *(uint2*)&DZh[smp * 136 + cb] = Q0;
                *(uint2*)&DZl[smp * 136 + cb] = Q1;
            }
        }
        __syncthreads();

        // ------- P4: dh1^T = e_w2 x dz2^T; wave owns htl=w; dz1 -> H1a/b ----
        {
            const unsigned short* DZh = (const unsigned short*)U;
            const unsigned short* DZl = DZh + 32 * 136;
            f32x4 acc0 = {0.f, 0.f, 0.f, 0.f};
            f32x4 acc1 = {0.f, 0.f, 0.f, 0.f};
            #pragma unroll
            for (int kc = 0; kc < 4; ++kc) {
                const int b0 = q * 136 + kc * 32 + g * 8;
                const int b1 = (16 + q) * 136 + kc * 32 + g * 8;
                s8b B0h = *(const s8b*)&DZh[b0];
                s8b B0l = *(const s8b*)&DZl[b0];
                s8b B1h = *(const s8b*)&DZh[b1];
                s8b B1l = *(const s8b*)&DZl[b1];
                const int wo = (w * 16 + q) * 128 + kc * 32 + g * 8;
                s8b Ah = *(const s8b*)&ew2bh[wo];
                s8b Al = *(const s8b*)&ew2bl[wo];
                acc0 = MFMA16(Ah, B0h, acc0);
                acc0 = MFMA16(Al, B0h, acc0);
                acc0 = MFMA16(Ah, B0l, acc0);
                acc1 = MFMA16(Ah, B1h, acc1);
                acc1 = MFMA16(Al, B1h, acc1);
                acc1 = MFMA16(Ah, B1l, acc1);
            }
            const int hb = w * 16 + g * 4;
            {   // ct = 0
                const int off = q * 136 + hb;
                const uint2 mh = *(const uint2*)&H1a[off];
                float v[4];
                v[0] = ((short)(mh.x & 0xffffu) > 0) ? acc0[0] : 0.f;
                v[1] = ((short)(mh.x >> 16)     > 0) ? acc0[1] : 0.f;
                v[2] = ((short)(mh.y & 0xffffu) > 0) ? acc0[2] : 0.f;
                v[3] = ((short)(mh.y >> 16)     > 0) ? acc0[3] : 0.f;
                uint2 Q0, Q1;
                split2pack4(v, Q0, Q1);
                *(uint2*)&H1a[off] = Q0;
                *(uint2*)&H1b[off] = Q1;
            }
            {   // ct = 1
                const int off = (16 + q) * 136 + hb;
                const uint2 mh = *(const uint2*)&H1a[off];
                float v[4];
                v[0] = ((short)(mh.x & 0xffffu) > 0) ? acc1[0] : 0.f;
                v[1] = ((short)(mh.x >> 16)     > 0) ? acc1[1] : 0.f;
                v[2] = ((short)(mh.y & 0xffffu) > 0) ? acc1[2] : 0.f;
                v[3] = ((short)(mh.y >> 16)     > 0) ? acc1[3] : 0.f;
                uint2 Q0, Q1;
                split2pack4(v, Q0, Q1);
                *(uint2*)&H1a[off] = Q0;
                *(uint2*)&H1b[off] = Q1;
            }
        }
        __syncthreads();

        // ------- P5: dy^T = Wdy x [da|dz1]^T ; y update (waves 0-3) ----------
        if (w < 4) {
            const int dt = w >> 1, st = w & 1;
            f32x4 acc = {0.f, 0.f, 0.f, 0.f};
            #pragma unroll
            for (int kc = 0; kc < 8; ++kc) {
                const int boff = (st * 16 + q) * 136 + (kc & 3) * 32 + g * 8;
                s8b bh, bl;
                if (kc < 4) { bh = *(const s8b*)&DAa[boff]; bl = *(const s8b*)&DAb[boff]; }
                else        { bh = *(const s8b*)&H1a[boff]; bl = *(const s8b*)&H1b[boff]; }
                const int aoff = (dt * 16 + q) * 256 + kc * 32 + g * 8;
                s8b ah = *(const s8b*)&Wdybh[aoff];
                s8b al = *(const s8b*)&Wdybl[aoff];
                acc = MFMA16(ah, bh, acc);
                acc = MFMA16(al, bh, acc);
                acc = MFMA16(ah, bl, acc);
            }
            const int smp = st * 16 + q;
            const int db = dt * 16 + g * 4;
            float4 yv4 = *(const float4*)&yS[smp * 36 + db];
            yv4.x -= LRf * (acc[0] + 2.f * REGf * yv4.x);
            yv4.y -= LRf * (acc[1] + 2.f * REGf * yv4.y);
            yv4.z -= LRf * (acc[2] + 2.f * REGf * yv4.z);
            yv4.w -= LRf * (acc[3] + 2.f * REGf * yv4.w);
            *(float4*)&yS[smp * 36 + db] = yv4;
        }
        __syncthreads();
    }

    // ---------- write out (512 threads x float2) ----------
    {
        const int orow = t >> 4;
        const int d2 = (t & 15) * 2;
        *(float2*)&yout[(size_t)(r0 + orow) * 32 + d2] =
            *(const float2*)&yS[orow * 36 + d2];
    }
}

// ---------------------------------------------------------------------------
extern "C" void kernel_launch(void* const* d_in, const int* in_sizes, int n_in,
                              void* d_out, int out_size, void* d_ws, size_t ws_size,
                              hipStream_t stream)
{
    const float* x      = (const float*)d_in[0];
    const int*   tin    = (const int*)d_in[1];
    const float* e_w1   = (const float*)d_in[2];
    const float* e_b1   = (const float*)d_in[3];
    const float* e_w2   = (const float*)d_in[4];
    const float* e_b2   = (const float*)d_in[5];
    const float* e_w3   = (const float*)d_in[6];
    const float* s_xw   = (const float*)d_in[8];
    const float* s_xb   = (const float*)d_in[9];
    const float* s_yw   = (const float*)d_in[10];
    const float* s_yb   = (const float*)d_in[11];
    const float* s_temb = (const float*)d_in[12];
    const float* s_t1w  = (const float*)d_in[13];
    const float* s_t1b  = (const float*)d_in[14];
    const float* s_t2w  = (const float*)d_in[15];
    const float* s_t2b  = (const float*)d_in[16];
    const float* tr1w   = (const float*)d_in[17];
    const float* tr1b   = (const float*)d_in[18];
    const float* tr2w   = (const float*)d_in[19];
    const float* tr2b   = (const float*)d_in[20];
    const int*   steps  = (const int*)d_in[21];

    const int B = in_sizes[0] / DXc;

    float* ws   = (float*)d_ws;
    float* hxeP = ws;
    float* cbP  = hxeP + (size_t)B * 128;
    float* d0   = cbP  + (size_t)B * 128;

    unsigned short* W1Tb0   = (unsigned short*)(d0 + 4 * 128);
    unsigned short* W1Tb1   = W1Tb0   + 256 * 32;
    unsigned short* W1Tb2   = W1Tb1   + 256 * 32;
    unsigned short* ew2Tb0  = W1Tb2   + 256 * 32;
    unsigned short* ew2Tb1  = ew2Tb0  + 128 * 128;
    unsigned short* ew2Tb2  = ew2Tb1  + 128 * 128;
    unsigned short* ew2bh   = ew2Tb2  + 128 * 128;
    unsigned short* ew2bl   = ew2bh   + 128 * 128;
    unsigned short* Wdybh   = ew2bl   + 128 * 128;
    unsigned short* Wdybl   = Wdybh   + 32 * 256;
    unsigned short* WcatTb0 = Wdybl   + 32 * 256;
    unsigned short* WcatTb1 = WcatTb0 + 256 * 256;
    unsigned short* WcatTb2 = WcatTb1 + 256 * 256;

    setup_kernel<<<68, 256, 0, stream>>>(e_w1, s_xw, s_yw, s_temb, s_t1w, s_t1b,
                                         s_t2w, s_t2b, tr1w, tr1b, s_xb, s_yb,
                                         e_w2, d0,
                                         WcatTb0, WcatTb1, WcatTb2,
                                         W1Tb0, W1Tb1, W1Tb2,
                                         ew2Tb0, ew2Tb1, ew2Tb2,
                                         ew2bh, ew2bl, Wdybh, Wdybl);
    rowpre_kernel<<<B / 64, 256, 0, stream>>>(x, tin, WcatTb0, WcatTb1, WcatTb2,
                                              e_b1, d0, hxeP, cbP);
    iterate_kernel<<<B / 32, 512, 0, stream>>>(hxeP, cbP,
                                               W1Tb0, W1Tb1, W1Tb2,
                                               ew2Tb0, ew2Tb1, ew2Tb2,
                                               ew2bh, ew2bl, Wdybh, Wdybl,
                                               e_w3, tr2w, tr2b, e_b2, tin,
                                               steps, (float*)d_out);
}

// Round 6
// 2816.253 us; speedup vs baseline: 1.5354x; 1.5354x over previous
//
#include <hip/hip_runtime.h>
#include <hip/hip_bf16.h>

#define DXc 256
#define DYc 32
#define Kc 4
#define Hc 128
#define LRf 0.1f
#define REGf 0.01f
#define TSTEPS 1000

typedef __attribute__((ext_vector_type(8))) short s8b;    // 8 x bf16 (4 VGPRs)
typedef __attribute__((ext_vector_type(4))) float f32x4;  // MFMA accumulator

#define MFMA16(a, b, c) __builtin_amdgcn_mfma_f32_16x16x32_bf16((a), (b), (c), 0, 0, 0)

// 6-product "f32-exact" MFMA: A=a0+a1+a2, B=b0+b1+b2 (exact 3-way bf16 splits).
#define MFMA6(A0, A1, A2, B0, B1, B2, acc)      \
    do {                                        \
        acc = MFMA16((A0), (B0), acc);          \
        acc = MFMA16((A0), (B1), acc);          \
        acc = MFMA16((A1), (B0), acc);          \
        acc = MFMA16((A0), (B2), acc);          \
        acc = MFMA16((A1), (B1), acc);          \
        acc = MFMA16((A2), (B0), acc);          \
    } while (0)

// ---- bf16 split helpers ----
__device__ __forceinline__ float hipart(float a) {
    return __uint_as_float(__float_as_uint(a) & 0xffff0000u);
}
__device__ __forceinline__ unsigned hi2(float a, float b) {
    return (__float_as_uint(a) >> 16) | (__float_as_uint(b) & 0xffff0000u);
}
__device__ __forceinline__ void wsplit(float x, unsigned short* __restrict__ h,
                                       unsigned short* __restrict__ l) {
    unsigned u = __float_as_uint(x);
    *h = (unsigned short)(u >> 16);
    float hf = __uint_as_float(u & 0xffff0000u);
    *l = (unsigned short)(__float_as_uint(x - hf) >> 16);
}
__device__ __forceinline__ void wsplit3(float x, unsigned short* __restrict__ p0,
                                        unsigned short* __restrict__ p1,
                                        unsigned short* __restrict__ p2) {
    unsigned u = __float_as_uint(x);
    *p0 = (unsigned short)(u >> 16);
    float r1 = x - __uint_as_float(u & 0xffff0000u);
    unsigned u1 = __float_as_uint(r1);
    *p1 = (unsigned short)(u1 >> 16);
    float r2 = r1 - __uint_as_float(u1 & 0xffff0000u);
    *p2 = (unsigned short)(__float_as_uint(r2) >> 16);
}
__device__ __forceinline__ void split3x8(const float* v, s8b& A0, s8b& A1, s8b& A2) {
    union { s8b s; unsigned u[4]; } P0, P1, P2;
    #pragma unroll
    for (int m = 0; m < 4; ++m) {
        float a = v[2 * m], b = v[2 * m + 1];
        unsigned ua = __float_as_uint(a), ub = __float_as_uint(b);
        P0.u[m] = (ua >> 16) | (ub & 0xffff0000u);
        float ra = a - __uint_as_float(ua & 0xffff0000u);
        float rb = b - __uint_as_float(ub & 0xffff0000u);
        unsigned ura = __float_as_uint(ra), urb = __float_as_uint(rb);
        P1.u[m] = (ura >> 16) | (urb & 0xffff0000u);
        float ra2 = ra - __uint_as_float(ura & 0xffff0000u);
        float rb2 = rb - __uint_as_float(urb & 0xffff0000u);
        P2.u[m] = (__float_as_uint(ra2) >> 16) | (__float_as_uint(rb2) & 0xffff0000u);
    }
    A0 = P0.s; A1 = P1.s; A2 = P2.s;
}
__device__ __forceinline__ void split3pack4(const float* v, uint2& Q0, uint2& Q1, uint2& Q2) {
    float r1[4], r2[4];
    #pragma unroll
    for (int i = 0; i < 4; ++i) {
        r1[i] = v[i] - hipart(v[i]);
        r2[i] = r1[i] - hipart(r1[i]);
    }
    Q0.x = hi2(v[0], v[1]);   Q0.y = hi2(v[2], v[3]);
    Q1.x = hi2(r1[0], r1[1]); Q1.y = hi2(r1[2], r1[3]);
    Q2.x = hi2(r2[0], r2[1]); Q2.y = hi2(r2[2], r2[3]);
}
__device__ __forceinline__ void split2pack4(const float* v, uint2& Q0, uint2& Q1) {
    Q0.x = hi2(v[0], v[1]); Q0.y = hi2(v[2], v[3]);
    float r0 = v[0] - hipart(v[0]), r1 = v[1] - hipart(v[1]);
    float r2 = v[2] - hipart(v[2]), r3 = v[3] - hipart(v[3]);
    Q1.x = hi2(r0, r1); Q1.y = hi2(r2, r3);
}

// ---------------------------------------------------------------------------
// Setup: derived weights into workspace (all bf16 split planes, k-contiguous).
// ---------------------------------------------------------------------------
__global__ __launch_bounds__(256) void setup_kernel(
    const float* __restrict__ e_w1, const float* __restrict__ s_xw,
    const float* __restrict__ s_yw, const float* __restrict__ s_temb,
    const float* __restrict__ s_t1w, const float* __restrict__ s_t1b,
    const float* __restrict__ s_t2w, const float* __restrict__ s_t2b,
    const float* __restrict__ tr1w, const float* __restrict__ tr1b,
    const float* __restrict__ s_xb, const float* __restrict__ s_yb,
    const float* __restrict__ e_w2, float* __restrict__ d0,
    unsigned short* __restrict__ WcatTb0, unsigned short* __restrict__ WcatTb1,
    unsigned short* __restrict__ WcatTb2,
    unsigned short* __restrict__ W1Tb0, unsigned short* __restrict__ W1Tb1,
    unsigned short* __restrict__ W1Tb2,
    unsigned short* __restrict__ ew2Tb0, unsigned short* __restrict__ ew2Tb1,
    unsigned short* __restrict__ ew2Tb2,
    unsigned short* __restrict__ ew2bh, unsigned short* __restrict__ ew2bl,
    unsigned short* __restrict__ Wdybh, unsigned short* __restrict__ Wdybl)
{
    const int b = blockIdx.x;
    const int t = threadIdx.x;
    if (b < 64) {
        #pragma unroll
        for (int i = 0; i < 2; ++i) {
            int idx = t + 256 * i;              // 0..511
            int k = 4 * b + (idx >> 7);
            int c = idx & 127;
            float acc = 0.f;
            for (int h = 0; h < 128; ++h)
                acc += s_xw[k * 128 + h] * tr1w[h * 128 + c];
            // WcatT[c][k]: E part (c) from e_w1, P part (128+c) computed
            wsplit3(acc, &WcatTb0[(128 + c) * 256 + k], &WcatTb1[(128 + c) * 256 + k],
                    &WcatTb2[(128 + c) * 256 + k]);
            float ev = e_w1[k * 128 + c];
            wsplit3(ev, &WcatTb0[c * 256 + k], &WcatTb1[c * 256 + k],
                    &WcatTb2[c * 256 + k]);
        }
    } else if (b == 64) {
        // M = s_yw @ A1   (W1 cols 128..255)
        #pragma unroll
        for (int i = 0; i < 16; ++i) {
            int idx = t + 256 * i;              // 0..4095
            int d = idx >> 7, c = idx & 127;
            float acc = 0.f;
            for (int h = 0; h < 128; ++h)
                acc += s_yw[d * 128 + h] * tr1w[(128 + h) * 128 + c];
            wsplit3(acc, &W1Tb0[(128 + c) * 32 + d], &W1Tb1[(128 + c) * 32 + d],
                    &W1Tb2[(128 + c) * 32 + d]);
            wsplit(acc, &Wdybh[d * 256 + c], &Wdybl[d * 256 + c]);
        }
    } else if (b == 65) {
        // Wy = e_w1[256:288]  (W1 cols 0..127)
        #pragma unroll
        for (int i = 0; i < 16; ++i) {
            int idx = t + 256 * i;
            int d = idx >> 7, c = idx & 127;
            float v = e_w1[(DXc + d) * 128 + c];
            wsplit3(v, &W1Tb0[c * 32 + d], &W1Tb1[c * 32 + d], &W1Tb2[c * 32 + d]);
            wsplit(v, &Wdybh[d * 256 + 128 + c], &Wdybl[d * 256 + 128 + c]);
        }
    } else if (b == 66) {
        // e_w2 splits (both orientations)
        #pragma unroll
        for (int i = 0; i < 64; ++i) {
            int idx = t + 256 * i;
            int h = idx >> 7, c = idx & 127;
            float v = e_w2[h * 128 + c];
            wsplit3(v, &ew2Tb0[c * 128 + h], &ew2Tb1[c * 128 + h],
                    &ew2Tb2[c * 128 + h]);
            wsplit(v, &ew2bh[h * 128 + c], &ew2bl[h * 128 + c]);
        }
    } else {
        // b == 67: th table then d0 table
        __shared__ float thS[4][128];
        #pragma unroll
        for (int i = 0; i < 2; ++i) {
            int idx = t + 256 * i;              // 0..511
            int tt = idx >> 7, c = idx & 127;
            float tau = (float)tt / (float)TSTEPS;
            if (tau < 1e-6f) tau = 1e-6f;
            float acc = s_t2b[c];
            for (int h = 0; h < 128; ++h) {
                float aa = tau * s_t1w[h] + s_t1b[h];
                float s = 1.f / (1.f + expf(-aa));
                acc += aa * s * s_t2w[h * 128 + c];
            }
            thS[tt][c] = acc;
        }
        __syncthreads();
        #pragma unroll
        for (int i = 0; i < 2; ++i) {
            int idx = t + 256 * i;
            int tt = idx >> 7, c = idx & 127;
            float acc = tr1b[c];
            for (int h = 0; h < 128; ++h) {
                acc += s_temb[tt * 128 + h] * tr1w[(256 + h) * 128 + c];
                acc += thS[tt][h]           * tr1w[(384 + h) * 128 + c];
                acc += s_yb[h]              * tr1w[(128 + h) * 128 + c];
                acc += s_xb[h]              * tr1w[h * 128 + c];
            }
            d0[tt * 128 + c] = acc;
        }
    }
}

// ---------------------------------------------------------------------------
// Row precompute (MFMA, transposed): [hxe|cb]^T = Wcat^T x x^T.
// ---------------------------------------------------------------------------
__global__ __launch_bounds__(256) void rowpre_kernel(
    const float* __restrict__ x, const int* __restrict__ tin,
    const unsigned short* __restrict__ WcatTb0,
    const unsigned short* __restrict__ WcatTb1,
    const unsigned short* __restrict__ WcatTb2,
    const float* __restrict__ e_b1, const float* __restrict__ d0,
    float* __restrict__ hxeP, float* __restrict__ cbP)
{
    __shared__ int tS[64];
    const int t = threadIdx.x;
    const int r0 = blockIdx.x * 64;
    const int w = t >> 6;
    const int l = t & 63;
    const int g = l >> 4, q = l & 15;
    if (t < 64) { int tv = tin[r0 + t]; tS[t] = tv > 0 ? tv : 0; }
    __syncthreads();

    for (int st = 0; st < 4; ++st) {
        const int smp = r0 + st * 16 + q;
        s8b Xb0[8], Xb1[8], Xb2[8];
        #pragma unroll
        for (int kc = 0; kc < 8; ++kc) {
            const float* xp = &x[(size_t)smp * 256 + kc * 32 + g * 8];
            float4 xa = *(const float4*)xp;
            float4 xb = *(const float4*)(xp + 4);
            float xv[8] = {xa.x, xa.y, xa.z, xa.w, xb.x, xb.y, xb.z, xb.w};
            split3x8(xv, Xb0[kc], Xb1[kc], Xb2[kc]);
        }
        #pragma unroll
        for (int ci = 0; ci < 4; ++ci) {
            const int colt = w * 4 + ci;
            f32x4 acc = {0.f, 0.f, 0.f, 0.f};
            #pragma unroll
            for (int kc = 0; kc < 8; ++kc) {
                const int wo = (colt * 16 + q) * 256 + kc * 32 + g * 8;
                s8b A0 = *(const s8b*)&WcatTb0[wo];
                s8b A1 = *(const s8b*)&WcatTb1[wo];
                s8b A2 = *(const s8b*)&WcatTb2[wo];
                MFMA6(A0, A1, A2, Xb0[kc], Xb1[kc], Xb2[kc], acc);
            }
            const int cb = colt * 16 + g * 4;
            if (colt < 8) {
                float4 bv = *(const float4*)&e_b1[cb];
                float4 o = {acc[0] + bv.x, acc[1] + bv.y, acc[2] + bv.z, acc[3] + bv.w};
                *(float4*)&hxeP[(size_t)smp * 128 + cb] = o;
            } else {
                const int cc = cb - 128;
                float4 dd = *(const float4*)&d0[tS[st * 16 + q] * 128 + cc];
                float4 o = {acc[0] + dd.x, acc[1] + dd.y, acc[2] + dd.z, acc[3] + dd.w};
                *(float4*)&cbP[(size_t)smp * 128 + cc] = o;
            }
        }
    }
}

// ---------------------------------------------------------------------------
// Iterate kernel: 32 rows/block, 8 waves (512 thr), 20 GD steps.
// __launch_bounds__(512) WITHOUT a min-waves arg: R5 evidence shows (512,4)
// forces VGPR=64 -> massive scratch spill (FETCH 67MB -> 8.2GB, 1.6x slower).
// Unconstrained alloc (~150-200 VGPR) still guarantees 2 waves/SIMD for a
// 512-thread block (cap 256) = 2x R3's occupancy, zero spill.
// P2 reindexed: thread p handles h in {4p..4p+3} u {64+4p..64+4p+3} ->
// U-row reads are 16 lanes x contiguous 256B (conflict-free) vs 128B-stride.
// ---------------------------------------------------------------------------
__global__ __launch_bounds__(512) void iterate_kernel(
    const float* __restrict__ hxeP, const float* __restrict__ cbP,
    const unsigned short* __restrict__ W1Tb0, const unsigned short* __restrict__ W1Tb1,
    const unsigned short* __restrict__ W1Tb2,
    const unsigned short* __restrict__ ew2Tb0, const unsigned short* __restrict__ ew2Tb1,
    const unsigned short* __restrict__ ew2Tb2,
    const unsigned short* __restrict__ ew2bh, const unsigned short* __restrict__ ew2bl,
    const unsigned short* __restrict__ Wdybh, const unsigned short* __restrict__ Wdybl,
    const float* __restrict__ e_w3, const float* __restrict__ tr2w,
    const float* __restrict__ tr2b, const float* __restrict__ e_b2,
    const int* __restrict__ tin, const int* __restrict__ stepsPtr,
    float* __restrict__ yout)
{
    __shared__ __align__(16) unsigned short H1a[32 * 136]; // h1 p0, then dz1 hi
    __shared__ __align__(16) unsigned short H1b[32 * 136]; // h1 p1, then dz1 lo
    __shared__ __align__(16) unsigned short H1c[32 * 136]; // h1 p2
    __shared__ __align__(16) unsigned short DAa[32 * 136], DAb[32 * 136]; // da hi/lo
    __shared__ __align__(16) float U[32 * 140];     // 'a' f32; then dz2 hi/lo bf16
    __shared__ __align__(16) float yS[32 * 36];     // y master f32 [sample][d]
    __shared__ float ew3S[512];
    __shared__ float eb2S[128];
    __shared__ float vSs[32];
    __shared__ int tcS[32];

    const int t = threadIdx.x;
    const int r0 = blockIdx.x * 32;
    const int w = t >> 6;        // wave 0..7
    const int l = t & 63;
    const int g = l >> 4;        // 0..3
    const int q = l & 15;        // 0..15
    const int row = t >> 4;      // P2 row 0..31
    const int p = t & 15;        // P2 h-slice
    const int hA = 4 * p;        // P2 h-set part 1: hA..hA+3
    const int hB = 64 + 4 * p;   // P2 h-set part 2: hB..hB+3

    if (t < 32) {
        int tv = tin[r0 + t];
        tcS[t] = tv > 0 ? tv : 0;
        vSs[t] = (tv >= 0) ? 1.f : 0.f;
    }
    if (t < 128) eb2S[t] = e_b2[t];
    ew3S[t] = e_w3[t];
    for (int i = t; i < 32 * 36; i += 512) yS[i] = 0.f;

    // tr2w rows for this thread's P2 h-set: 8 x float4 = 32 VGPR
    float4 trw4[8];
    #pragma unroll
    for (int j = 0; j < 4; ++j) {
        trw4[j]     = *(const float4*)&tr2w[(hA + j) * 4];
        trw4[4 + j] = *(const float4*)&tr2w[(hB + j) * 4];
    }
    // W1^T A-fragments (loop-invariant): 2 col-tiles x 3 planes = 24 VGPR
    s8b W1A0[2], W1A1[2], W1A2[2];
    #pragma unroll
    for (int ci = 0; ci < 2; ++ci) {
        const int arow = (2 * w + ci) * 16 + q;
        W1A0[ci] = *(const s8b*)&W1Tb0[arow * 32 + g * 8];
        W1A1[ci] = *(const s8b*)&W1Tb1[arow * 32 + g * 8];
        W1A2[ci] = *(const s8b*)&W1Tb2[arow * 32 + g * 8];
    }
    const float tb0 = tr2b[0], tb1 = tr2b[1], tb2 = tr2b[2], tb3 = tr2b[3];
    const int nsteps = stepsPtr[0];

    __syncthreads();

    for (int step = 0; step < nsteps; ++step) {
        // ------- P1: z1^T = W1^T x y^T; waves 0-3 -> h1, waves 4-7 -> 'a' ----
        #pragma unroll
        for (int ct = 0; ct < 2; ++ct) {
            float4 ya = *(const float4*)&yS[(ct * 16 + q) * 36 + g * 8];
            float4 yb = *(const float4*)&yS[(ct * 16 + q) * 36 + g * 8 + 4];
            float yv[8] = {ya.x, ya.y, ya.z, ya.w, yb.x, yb.y, yb.z, yb.w};
            s8b Y0, Y1, Y2;
            split3x8(yv, Y0, Y1, Y2);
            #pragma unroll
            for (int ci = 0; ci < 2; ++ci) {
                const int colt = 2 * w + ci;
                f32x4 acc = {0.f, 0.f, 0.f, 0.f};
                MFMA6(W1A0[ci], W1A1[ci], W1A2[ci], Y0, Y1, Y2, acc);
                if (w < 4) {
                    const float4 vb = *(const float4*)
                        &hxeP[(size_t)(r0 + ct * 16 + q) * 128 + colt * 16 + g * 4];
                    float v[4];
                    v[0] = acc[0] + vb.x; v[1] = acc[1] + vb.y;
                    v[2] = acc[2] + vb.z; v[3] = acc[3] + vb.w;
                    #pragma unroll
                    for (int j = 0; j < 4; ++j) v[j] = v[j] > 0.f ? v[j] : 0.f;
                    uint2 Q0, Q1, Q2;
                    split3pack4(v, Q0, Q1, Q2);
                    const int off = (ct * 16 + q) * 136 + colt * 16 + g * 4;
                    *(uint2*)&H1a[off] = Q0;
                    *(uint2*)&H1b[off] = Q1;
                    *(uint2*)&H1c[off] = Q2;
                } else {
                    const int cc = (colt - 8) * 16 + g * 4;
                    const float4 vb = *(const float4*)
                        &cbP[(size_t)(r0 + ct * 16 + q) * 128 + cc];
                    float4 o = {acc[0] + vb.x, acc[1] + vb.y,
                                acc[2] + vb.z, acc[3] + vb.w};
                    *(float4*)&U[(ct * 16 + q) * 140 + cc] = o;
                }
            }
        }
        __syncthreads();

        // ---------------- P2: pointwise CE (f32); 32 rows x 16 lanes ---------
        {
            float aval[8], sval[8];
            float lg0 = 0.f, lg1 = 0.f, lg2 = 0.f, lg3 = 0.f;
            float4 v0 = *(const float4*)&U[row * 140 + hA];
            float4 v1 = *(const float4*)&U[row * 140 + hB];
            aval[0] = v0.x; aval[1] = v0.y; aval[2] = v0.z; aval[3] = v0.w;
            aval[4] = v1.x; aval[5] = v1.y; aval[6] = v1.z; aval[7] = v1.w;
            #pragma unroll
            for (int j = 0; j < 8; ++j) {
                float a = aval[j];
                float s = 1.f / (1.f + __expf(-a));
                sval[j] = s;
                float u = a * s;
                lg0 += u * trw4[j].x; lg1 += u * trw4[j].y;
                lg2 += u * trw4[j].z; lg3 += u * trw4[j].w;
            }
            #pragma unroll
            for (int m = 1; m < 16; m <<= 1) {
                lg0 += __shfl_xor(lg0, m);
                lg1 += __shfl_xor(lg1, m);
                lg2 += __shfl_xor(lg2, m);
                lg3 += __shfl_xor(lg3, m);
            }
            lg0 += tb0; lg1 += tb1; lg2 += tb2; lg3 += tb3;
            float mx = fmaxf(fmaxf(lg0, lg1), fmaxf(lg2, lg3));
            float e0 = __expf(lg0 - mx), e1 = __expf(lg1 - mx);
            float e2 = __expf(lg2 - mx), e3 = __expf(lg3 - mx);
            float inv = 1.f / (e0 + e1 + e2 + e3);
            int tcr = tcS[row];
            float vd = vSs[row];
            float dl0 = (e0 * inv - (tcr == 0 ? 1.f : 0.f)) * vd;
            float dl1 = (e1 * inv - (tcr == 1 ? 1.f : 0.f)) * vd;
            float dl2 = (e2 * inv - (tcr == 2 ? 1.f : 0.f)) * vd;
            float dl3 = (e3 * inv - (tcr == 3 ? 1.f : 0.f)) * vd;
            #pragma unroll
            for (int j = 0; j < 8; ++j) {
                float a = aval[j], s = sval[j];
                float du = dl0 * trw4[j].x + dl1 * trw4[j].y
                         + dl2 * trw4[j].z + dl3 * trw4[j].w;
                aval[j] = du * s * (1.f + a * (1.f - s));   // da
            }
            float rl[8];
            #pragma unroll
            for (int j = 0; j < 8; ++j) rl[j] = aval[j] - hipart(aval[j]);
            uint2 QhA = {hi2(aval[0], aval[1]), hi2(aval[2], aval[3])};
            uint2 QhB = {hi2(aval[4], aval[5]), hi2(aval[6], aval[7])};
            uint2 QlA = {hi2(rl[0], rl[1]), hi2(rl[2], rl[3])};
            uint2 QlB = {hi2(rl[4], rl[5]), hi2(rl[6], rl[7])};
            *(uint2*)&DAa[row * 136 + hA] = QhA;
            *(uint2*)&DAa[row * 136 + hB] = QhB;
            *(uint2*)&DAb[row * 136 + hA] = QlA;
            *(uint2*)&DAb[row * 136 + hB] = QlB;
        }
        __syncthreads();

        // ------- P3: z2^T = e_w2^T x h1^T (hi-prec); wave owns ctl=w --------
        {
            unsigned short* DZh = (unsigned short*)U;
            unsigned short* DZl = DZh + 32 * 136;
            f32x4 acc0 = {0.f, 0.f, 0.f, 0.f};
            f32x4 acc1 = {0.f, 0.f, 0.f, 0.f};
            #pragma unroll
            for (int kc = 0; kc < 4; ++kc) {
                const int b0 = q * 136 + kc * 32 + g * 8;
                const int b1 = (16 + q) * 136 + kc * 32 + g * 8;
                s8b B0a = *(const s8b*)&H1a[b0];
                s8b B0b = *(const s8b*)&H1b[b0];
                s8b B0c = *(const s8b*)&H1c[b0];
                s8b B1a = *(const s8b*)&H1a[b1];
                s8b B1b = *(const s8b*)&H1b[b1];
                s8b B1c = *(const s8b*)&H1c[b1];
                const int wo = (w * 16 + q) * 128 + kc * 32 + g * 8;
                s8b A0 = *(const s8b*)&ew2Tb0[wo];
                s8b A1 = *(const s8b*)&ew2Tb1[wo];
                s8b A2 = *(const s8b*)&ew2Tb2[wo];
                MFMA6(A0, A1, A2, B0a, B0b, B0c, acc0);
                MFMA6(A0, A1, A2, B1a, B1b, B1c, acc1);
            }
            const int cb = w * 16 + g * 4;
            const float4 eb = *(const float4*)&eb2S[cb];
            {   // ct = 0
                const int smp = q;
                const int tcr = tcS[smp];
                float dz[4];
                dz[0] = (acc0[0] + eb.x) > 0.f ? ew3S[(cb + 0) * 4 + tcr] : 0.f;
                dz[1] = (acc0[1] + eb.y) > 0.f ? ew3S[(cb + 1) * 4 + tcr] : 0.f;
                dz[2] = (acc0[2] + eb.z) > 0.f ? ew3S[(cb + 2) * 4 + tcr] : 0.f;
                dz[3] = (acc0[3] + eb.w) > 0.f ? ew3S[(cb + 3) * 4 + tcr] : 0.f;
                uint2 Q0, Q1;
                split2pack4(dz, Q0, Q1);
                *(uint2*)&DZh[smp * 136 + cb] = Q0;
                *(uint2*)&DZl[smp * 136 + cb] = Q1;
            }
            {   // ct = 1
                const int smp = 16 + q;
                const int tcr = tcS[smp];
                float dz[4];
                dz[0] = (acc1[0] + eb.x) > 0.f ? ew3S[(cb + 0) * 4 + tcr] : 0.f;
                dz[1] = (acc1[1] + eb.y) > 0.f ? ew3S[(cb + 1) * 4 + tcr] : 0.f;
                dz[2] = (acc1[2] + eb.z) > 0.f ? ew3S[(cb + 2) * 4 + tcr] : 0.f;
                dz[3] = (acc1[3] + eb.w) > 0.f ? ew3S[(cb + 3) * 4 + tcr] : 0.f;
                uint2 Q0, Q1;
                split2pack4(dz, Q0, Q1);
                *(uint2*)&DZh[smp * 136 + cb] = Q0;
                *(uint2*)&DZl[smp * 136 + cb] = Q1;
            }
        }
        __syncthreads();

        // ------- P4: dh1^T = e_w2 x dz2^T; wave owns htl=w; dz1 -> H1a/b ----
        {
            const unsigned short* DZh = (const unsigned short*)U;
            const unsigned short* DZl = DZh + 32 * 136;
            f32x4 acc0 = {0.f, 0.f, 0.f, 0.f};
            f32x4 acc1 = {0.f, 0.f, 0.f, 0.f};
            #pragma unroll
            for (int kc = 0; kc < 4; ++kc) {
                const int b0 = q * 136 + kc * 32 + g * 8;
                const int b1 = (16 + q) * 136 + kc * 32 + g * 8;
                s8b B0h = *(const s8b*)&DZh[b0];
                s8b B0l = *(const s8b*)&DZl[b0];
                s8b B1h = *(const s8b*)&DZh[b1];
                s8b B1l = *(const s8b*)&DZl[b1];
                const int wo = (w * 16 + q) * 128 + kc * 32 + g * 8;
                s8b Ah = *(const s8b*)&ew2bh[wo];
                s8b Al = *(const s8b*)&ew2bl[wo];
                acc0 = MFMA16(Ah, B0h, acc0);
                acc0 = MFMA16(Al, B0h, acc0);
                acc0 = MFMA16(Ah, B0l, acc0);
                acc1 = MFMA16(Ah, B1h, acc1);
                acc1 = MFMA16(Al, B1h, acc1);
                acc1 = MFMA16(Ah, B1l, acc1);
            }
            const int hb = w * 16 + g * 4;
            {   // ct = 0
                const int off = q * 136 + hb;
                const uint2 mh = *(const uint2*)&H1a[off];
                float v[4];
                v[0] = ((short)(mh.x & 0xffffu) > 0) ? acc0[0] : 0.f;
                v[1] = ((short)(mh.x >> 16)     > 0) ? acc0[1] : 0.f;
                v[2] = ((short)(mh.y & 0xffffu) > 0) ? acc0[2] : 0.f;
                v[3] = ((short)(mh.y >> 16)     > 0) ? acc0[3] : 0.f;
                uint2 Q0, Q1;
                split2pack4(v, Q0, Q1);
                *(uint2*)&H1a[off] = Q0;
                *(uint2*)&H1b[off] = Q1;
            }
            {   // ct = 1
                const int off = (16 + q) * 136 + hb;
                const uint2 mh = *(const uint2*)&H1a[off];
                float v[4];
                v[0] = ((short)(mh.x & 0xffffu) > 0) ? acc1[0] : 0.f;
                v[1] = ((short)(mh.x >> 16)     > 0) ? acc1[1] : 0.f;
                v[2] = ((short)(mh.y & 0xffffu) > 0) ? acc1[2] : 0.f;
                v[3] = ((short)(mh.y >> 16)     > 0) ? acc1[3] : 0.f;
                uint2 Q0, Q1;
                split2pack4(v, Q0, Q1);
                *(uint2*)&H1a[off] = Q0;
                *(uint2*)&H1b[off] = Q1;
            }
        }
        __syncthreads();

        // ------- P5: dy^T = Wdy x [da|dz1]^T ; y update (waves 0-3) ----------
        if (w < 4) {
            const int dt = w >> 1, st = w & 1;
            f32x4 acc = {0.f, 0.f, 0.f, 0.f};
            #pragma unroll
            for (int kc = 0; kc < 8; ++kc) {
                const int boff = (st * 16 + q) * 136 + (kc & 3) * 32 + g * 8;
                s8b bh, bl;
                if (kc < 4) { bh = *(const s8b*)&DAa[boff]; bl = *(const s8b*)&DAb[boff]; }
                else        { bh = *(const s8b*)&H1a[boff]; bl = *(const s8b*)&H1b[boff]; }
                const int aoff = (dt * 16 + q) * 256 + kc * 32 + g * 8;
                s8b ah = *(const s8b*)&Wdybh[aoff];
                s8b al = *(const s8b*)&Wdybl[aoff];
                acc = MFMA16(ah, bh, acc);
                acc = MFMA16(al, bh, acc);
                acc = MFMA16(ah, bl, acc);
            }
            const int smp = st * 16 + q;
            const int db = dt * 16 + g * 4;
            float4 yv4 = *(const float4*)&yS[smp * 36 + db];
            yv4.x -= LRf * (acc[0] + 2.f * REGf * yv4.x);
            yv4.y -= LRf * (acc[1] + 2.f * REGf * yv4.y);
            yv4.z -= LRf * (acc[2] + 2.f * REGf * yv4.z);
            yv4.w -= LRf * (acc[3] + 2.f * REGf * yv4.w);
            *(float4*)&yS[smp * 36 + db] = yv4;
        }
        __syncthreads();
    }

    // ---------- write out (512 threads x float2) ----------
    {
        const int orow = t >> 4;
        const int d2 = (t & 15) * 2;
        *(float2*)&yout[(size_t)(r0 + orow) * 32 + d2] =
            *(const float2*)&yS[orow * 36 + d2];
    }
}

// ---------------------------------------------------------------------------
extern "C" void kernel_launch(void* const* d_in, const int* in_sizes, int n_in,
                              void* d_out, int out_size, void* d_ws, size_t ws_size,
                              hipStream_t stream)
{
    const float* x      = (const float*)d_in[0];
    const int*   tin    = (const int*)d_in[1];
    const float* e_w1   = (const float*)d_in[2];
    const float* e_b1   = (const float*)d_in[3];
    const float* e_w2   = (const float*)d_in[4];
    const float* e_b2   = (const float*)d_in[5];
    const float* e_w3   = (const float*)d_in[6];
    const float* s_xw   = (const float*)d_in[8];
    const float* s_xb   = (const float*)d_in[9];
    const float* s_yw   = (const float*)d_in[10];
    const float* s_yb   = (const float*)d_in[11];
    const float* s_temb = (const float*)d_in[12];
    const float* s_t1w  = (const float*)d_in[13];
    const float* s_t1b  = (const float*)d_in[14];
    const float* s_t2w  = (const float*)d_in[15];
    const float* s_t2b  = (const float*)d_in[16];
    const float* tr1w   = (const float*)d_in[17];
    const float* tr1b   = (const float*)d_in[18];
    const float* tr2w   = (const float*)d_in[19];
    const float* tr2b   = (const float*)d_in[20];
    const int*   steps  = (const int*)d_in[21];

    const int B = in_sizes[0] / DXc;

    float* ws   = (float*)d_ws;
    float* hxeP = ws;
    float* cbP  = hxeP + (size_t)B * 128;
    float* d0   = cbP  + (size_t)B * 128;

    unsigned short* W1Tb0   = (unsigned short*)(d0 + 4 * 128);
    unsigned short* W1Tb1   = W1Tb0   + 256 * 32;
    unsigned short* W1Tb2   = W1Tb1   + 256 * 32;
    unsigned short* ew2Tb0  = W1Tb2   + 256 * 32;
    unsigned short* ew2Tb1  = ew2Tb0  + 128 * 128;
    unsigned short* ew2Tb2  = ew2Tb1  + 128 * 128;
    unsigned short* ew2bh   = ew2Tb2  + 128 * 128;
    unsigned short* ew2bl   = ew2bh   + 128 * 128;
    unsigned short* Wdybh   = ew2bl   + 128 * 128;
    unsigned short* Wdybl   = Wdybh   + 32 * 256;
    unsigned short* WcatTb0 = Wdybl   + 32 * 256;
    unsigned short* WcatTb1 = WcatTb0 + 256 * 256;
    unsigned short* WcatTb2 = WcatTb1 + 256 * 256;

    setup_kernel<<<68, 256, 0, stream>>>(e_w1, s_xw, s_yw, s_temb, s_t1w, s_t1b,
                                         s_t2w, s_t2b, tr1w, tr1b, s_xb, s_yb,
                                         e_w2, d0,
                                         WcatTb0, WcatTb1, WcatTb2,
                                         W1Tb0, W1Tb1, W1Tb2,
                                         ew2Tb0, ew2Tb1, ew2Tb2,
                                         ew2bh, ew2bl, Wdybh, Wdybl);
    rowpre_kernel<<<B / 64, 256, 0, stream>>>(x, tin, WcatTb0, WcatTb1, WcatTb2,
                                              e_b1, d0, hxeP, cbP);
    iterate_kernel<<<B / 32, 512, 0, stream>>>(hxeP, cbP,
                                               W1Tb0, W1Tb1, W1Tb2,
                                               ew2Tb0, ew2Tb1, ew2Tb2,
                                               ew2bh, ew2bl, Wdybh, Wdybl,
                                               e_w3, tr2w, tr2b, e_b2, tin,
                                               steps, (float*)d_out);
}